// Round 1
// baseline (478.932 us; speedup 1.0000x reference)
//
#include <hip/hip_runtime.h>
#include <hip/hip_bf16.h>

#define N_NODES 512
#define N_EDGES (512 * 512)

// ---------------------------------------------------------------------------
// Counting sort of edges by dst: count -> exclusive scan -> scatter-permute
// ---------------------------------------------------------------------------
__global__ __launch_bounds__(256) void count_kernel(const int* __restrict__ dst,
                                                    int* __restrict__ cnt, int E) {
    int e = blockIdx.x * 256 + threadIdx.x;
    if (e < E) atomicAdd(&cnt[dst[e]], 1);
}

__global__ __launch_bounds__(512) void scan_kernel(const int* __restrict__ cnt,
                                                   int* __restrict__ offs,
                                                   int* __restrict__ cursor) {
    __shared__ int buf[N_NODES];
    int t = threadIdx.x;
    int v = cnt[t];
    buf[t] = v;
    __syncthreads();
    // Hillis-Steele inclusive scan over 512 elements
    for (int d = 1; d < N_NODES; d <<= 1) {
        int add = (t >= d) ? buf[t - d] : 0;
        __syncthreads();
        buf[t] += add;
        __syncthreads();
    }
    offs[t + 1] = buf[t];
    if (t == 0) offs[0] = 0;
    cursor[t] = buf[t] - v;  // exclusive prefix = bucket start
}

__global__ __launch_bounds__(256) void scatter_kernel(const int* __restrict__ src,
                                                      const int* __restrict__ dst,
                                                      const float* __restrict__ ea,
                                                      int* __restrict__ cursor,
                                                      int* __restrict__ src_s,
                                                      float* __restrict__ ea_s, int E) {
    int e = blockIdx.x * 256 + threadIdx.x;
    if (e < E) {
        int p = atomicAdd(&cursor[dst[e]], 1);
        src_s[p] = src[e];
#pragma unroll
        for (int v = 0; v < 6; v++) ea_s[p * 6 + v] = ea[e * 6 + v];
    }
}

// ---------------------------------------------------------------------------
// NNConv layer: one block per dst node. Lanes own edge-MLP output columns j
// (j = i*COUT + o); We[:,j], be[j] are register-resident for the whole block.
// Edges stream serially (uniform addresses -> scalar loads), chunked by 8 for
// latency hiding. h_prev for all nodes is staged in LDS.
// ---------------------------------------------------------------------------
template <int CIN, int COUT>
__global__ __launch_bounds__(256) void nnconv_kernel(
    const float* __restrict__ hprev,  // [512, CIN]
    const float* __restrict__ ea_s,   // [E, 6] sorted by dst
    const int* __restrict__ src_s,    // [E]
    const int* __restrict__ offs,     // [513]
    const float* __restrict__ We,     // [6, CIN*COUT]
    const float* __restrict__ be,     // [CIN*COUT]
    const float* __restrict__ root,   // [CIN, COUT]
    const float* __restrict__ bias,   // [COUT]
    float* __restrict__ hout)         // [512, COUT]
{
    constexpr int J = CIN * COUT;
    constexpr int SLOTS = (J + 255) / 256;

    __shared__ float lds_x[N_NODES * CIN];
    __shared__ float lds_acc[J];

    const int n = blockIdx.x;
    const int tid = threadIdx.x;

    // stage h_prev for all nodes
    for (int idx = tid; idx < N_NODES * CIN; idx += 256) lds_x[idx] = hprev[idx];

    // register-resident edge-MLP weights (zero-padded for idle slots)
    float wr[SLOTS][6], ber[SLOTS], acc[SLOTS];
    int iof[SLOTS];
#pragma unroll
    for (int s = 0; s < SLOTS; s++) {
        int j = tid + s * 256;
        acc[s] = 0.f;
        if (j < J) {
            ber[s] = be[j];
#pragma unroll
            for (int v = 0; v < 6; v++) wr[s][v] = We[v * J + j];
            iof[s] = j / COUT;
        } else {
            ber[s] = 0.f;
#pragma unroll
            for (int v = 0; v < 6; v++) wr[s][v] = 0.f;
            iof[s] = 0;
        }
    }
    __syncthreads();

    const int start = offs[n];
    const int end = offs[n + 1];

    int p = start;
    // main loop, 8-edge chunks: batch uniform loads, then compute
    for (; p + 8 <= end; p += 8) {
        float ea[8][6];
        int sv[8];
#pragma unroll
        for (int u = 0; u < 8; u++) {
            sv[u] = src_s[p + u];
#pragma unroll
            for (int v = 0; v < 6; v++) ea[u][v] = ea_s[(p + u) * 6 + v];
        }
#pragma unroll
        for (int u = 0; u < 8; u++) {
#pragma unroll
            for (int s = 0; s < SLOTS; s++) {
                float a = ber[s];
#pragma unroll
                for (int v = 0; v < 6; v++) a = fmaf(ea[u][v], wr[s][v], a);
                float xv = lds_x[sv[u] * CIN + iof[s]];
                acc[s] = fmaf(xv, fmaxf(a, 0.f), acc[s]);
            }
        }
    }
    // tail
    for (; p < end; ++p) {
        float ea[6];
        int sv = src_s[p];
#pragma unroll
        for (int v = 0; v < 6; v++) ea[v] = ea_s[p * 6 + v];
#pragma unroll
        for (int s = 0; s < SLOTS; s++) {
            float a = ber[s];
#pragma unroll
            for (int v = 0; v < 6; v++) a = fmaf(ea[v], wr[s][v], a);
            float xv = lds_x[sv * CIN + iof[s]];
            acc[s] = fmaf(xv, fmaxf(a, 0.f), acc[s]);
        }
    }

    // deposit per-j partials, then reduce over i for each o
    __syncthreads();
#pragma unroll
    for (int s = 0; s < SLOTS; s++) {
        int j = tid + s * 256;
        if (j < J) lds_acc[j] = acc[s];
    }
    __syncthreads();

    if (tid < COUT) {
        int cnt = end - start;
        float inv = 1.0f / fmaxf((float)cnt, 1.0f);
        float aggv = 0.f;
#pragma unroll
        for (int i = 0; i < CIN; i++) aggv += lds_acc[i * COUT + tid];
        aggv *= inv;
        float r = 0.f;
#pragma unroll
        for (int i = 0; i < CIN; i++) r = fmaf(lds_x[n * CIN + i], root[i * COUT + tid], r);
        float outv = aggv + r + bias[tid];
        hout[n * COUT + tid] = fmaxf(outv, 0.f);  // outer relu of the layer
    }
}

// ---------------------------------------------------------------------------
// CBT: out[i,j] = sum_k |h3[i,k] - h3[j,k]|, h3 is [512,5]
// ---------------------------------------------------------------------------
__global__ __launch_bounds__(256) void cbt_kernel(const float* __restrict__ h3,
                                                  float* __restrict__ out) {
    __shared__ float lh[N_NODES * 5];
    int tid = threadIdx.x;
    for (int idx = tid; idx < N_NODES * 5; idx += 256) lh[idx] = h3[idx];
    __syncthreads();
    int i = blockIdx.x;
    float hi[5];
#pragma unroll
    for (int k = 0; k < 5; k++) hi[k] = lh[i * 5 + k];
    for (int j = tid; j < N_NODES; j += 256) {
        float sacc = 0.f;
#pragma unroll
        for (int k = 0; k < 5; k++) sacc += fabsf(hi[k] - lh[j * 5 + k]);
        out[i * N_NODES + j] = sacc;
    }
}

// ---------------------------------------------------------------------------
extern "C" void kernel_launch(void* const* d_in, const int* in_sizes, int n_in,
                              void* d_out, int out_size, void* d_ws, size_t ws_size,
                              hipStream_t stream) {
    const float* x = (const float*)d_in[0];
    const float* edge_attr = (const float*)d_in[1];
    const int* edge_index = (const int*)d_in[2];
    const float* We1 = (const float*)d_in[3];
    const float* be1 = (const float*)d_in[4];
    const float* root1 = (const float*)d_in[5];
    const float* b1 = (const float*)d_in[6];
    const float* We2 = (const float*)d_in[7];
    const float* be2 = (const float*)d_in[8];
    const float* root2 = (const float*)d_in[9];
    const float* b2 = (const float*)d_in[10];
    const float* We3 = (const float*)d_in[11];
    const float* be3 = (const float*)d_in[12];
    const float* root3 = (const float*)d_in[13];
    const float* b3 = (const float*)d_in[14];

    const int E = N_EDGES;
    const int* src = edge_index;
    const int* dst = edge_index + E;

    char* ws = (char*)d_ws;
    int* cnt = (int*)(ws + 0);              // 512 ints
    int* offs = (int*)(ws + 4096);          // 513 ints
    int* cursor = (int*)(ws + 8192);        // 512 ints
    int* src_s = (int*)(ws + 12288);        // E ints -> ends 1,060,864
    float* ea_s = (float*)(ws + 1060864);   // E*6 floats -> ends 7,352,320
    float* h1 = (float*)(ws + 7352320);     // 512*36
    float* h2 = (float*)(ws + 7426048);     // 512*24
    float* h3 = (float*)(ws + 7475200);     // 512*5

    hipMemsetAsync(cnt, 0, N_NODES * sizeof(int), stream);
    count_kernel<<<E / 256, 256, 0, stream>>>(dst, cnt, E);
    scan_kernel<<<1, 512, 0, stream>>>(cnt, offs, cursor);
    scatter_kernel<<<E / 256, 256, 0, stream>>>(src, dst, edge_attr, cursor, src_s, ea_s, E);

    nnconv_kernel<1, 36><<<N_NODES, 256, 0, stream>>>(x, ea_s, src_s, offs, We1, be1, root1, b1, h1);
    nnconv_kernel<36, 24><<<N_NODES, 256, 0, stream>>>(h1, ea_s, src_s, offs, We2, be2, root2, b2, h2);
    nnconv_kernel<24, 5><<<N_NODES, 256, 0, stream>>>(h2, ea_s, src_s, offs, We3, be3, root3, b3, h3);

    cbt_kernel<<<N_NODES, 256, 0, stream>>>(h3, (float*)d_out);
}

// Round 2
// 307.647 us; speedup vs baseline: 1.5568x; 1.5568x over previous
//
#include <hip/hip_runtime.h>
#include <hip/hip_bf16.h>

#define N_NODES 512
#define N_EDGES (512 * 512)

// ---------------------------------------------------------------------------
// Counting sort of edges by dst (keys only): LDS-histogram count -> scan ->
// scatter (src, eid) pairs. edge_attr stays in place; nnconv gathers by eid.
// ---------------------------------------------------------------------------
__global__ __launch_bounds__(256) void count_kernel(const int* __restrict__ dst,
                                                    int* __restrict__ cnt, int E) {
    __shared__ int h[N_NODES];
    int tid = threadIdx.x;
    for (int i = tid; i < N_NODES; i += 256) h[i] = 0;
    __syncthreads();
    for (int e = blockIdx.x * 256 + tid; e < E; e += gridDim.x * 256)
        atomicAdd(&h[dst[e]], 1);
    __syncthreads();
    for (int i = tid; i < N_NODES; i += 256) {
        int v = h[i];
        if (v) atomicAdd(&cnt[i], v);
    }
}

__global__ __launch_bounds__(512) void scan_kernel(const int* __restrict__ cnt,
                                                   int* __restrict__ offs,
                                                   int* __restrict__ cursor) {
    __shared__ int buf[N_NODES];
    int t = threadIdx.x;
    int v = cnt[t];
    buf[t] = v;
    __syncthreads();
    for (int d = 1; d < N_NODES; d <<= 1) {
        int add = (t >= d) ? buf[t - d] : 0;
        __syncthreads();
        buf[t] += add;
        __syncthreads();
    }
    offs[t + 1] = buf[t];
    if (t == 0) offs[0] = 0;
    cursor[t] = buf[t] - v;  // exclusive prefix = bucket start
}

__global__ __launch_bounds__(256) void scatter_kernel(const int* __restrict__ src,
                                                      const int* __restrict__ dst,
                                                      int* __restrict__ cursor,
                                                      int2* __restrict__ pairs, int E) {
    int e = blockIdx.x * 256 + threadIdx.x;
    if (e < E) {
        int p = atomicAdd(&cursor[dst[e]], 1);
        pairs[p] = make_int2(src[e], e);
    }
}

// ---------------------------------------------------------------------------
// NNConv edge pipeline: grid = N_NODES * G blocks; block (n,g) processes slice
// g of node n's edge segment. Lanes own edge-MLP columns j=(i,o); We[:,j], be[j]
// register-resident. Edges stream in 8-chunks with uniform (scalar-friendly)
// loads; x[src] gathered from global (cache-resident). Partial sums combined
// by atomicAdd into agg[n, o].
// ---------------------------------------------------------------------------
template <int CIN, int COUT, int BLK, int G>
__global__ __launch_bounds__(BLK) void nnconv_edges(
    const float* __restrict__ hprev,  // [512, CIN]
    const float* __restrict__ ea,     // [E, 6] original order
    const int2* __restrict__ pairs,   // [E] (src, eid) sorted by dst
    const int* __restrict__ offs,     // [513]
    const float* __restrict__ We,     // [6, CIN*COUT]
    const float* __restrict__ be,     // [CIN*COUT]
    float* __restrict__ agg)          // [512, COUT] pre-zeroed
{
    constexpr int J = CIN * COUT;
    constexpr int SLOTS = (J + BLK - 1) / BLK;
    __shared__ float lds_acc[J];

    const int n = blockIdx.x / G;
    const int g = blockIdx.x % G;
    const int tid = threadIdx.x;

    float wr[SLOTS][6], ber[SLOTS], acc[SLOTS];
    int iof[SLOTS];
#pragma unroll
    for (int s = 0; s < SLOTS; s++) {
        int j = tid + s * BLK;
        bool ok = (j < J);
        acc[s] = 0.f;
        ber[s] = ok ? be[j] : 0.f;
        iof[s] = ok ? (j / COUT) : 0;
#pragma unroll
        for (int v = 0; v < 6; v++) wr[s][v] = ok ? We[v * J + j] : 0.f;
    }

    const int start = offs[n];
    const int end = offs[n + 1];
    const int len = end - start;
    const int per = (len + G - 1) / G;
    int p = start + g * per;
    int p1 = p + per;
    if (p1 > end) p1 = end;

    for (; p + 8 <= p1; p += 8) {
        int sv[8], eid[8];
        float ear[8][6];
#pragma unroll
        for (int u = 0; u < 8; u++) {
            int2 pr = pairs[p + u];
            sv[u] = pr.x;
            eid[u] = pr.y;
        }
#pragma unroll
        for (int u = 0; u < 8; u++) {
            const float2* e2 = (const float2*)(ea + (size_t)eid[u] * 6);
            float2 a = e2[0], b = e2[1], c = e2[2];
            ear[u][0] = a.x; ear[u][1] = a.y; ear[u][2] = b.x;
            ear[u][3] = b.y; ear[u][4] = c.x; ear[u][5] = c.y;
        }
#pragma unroll
        for (int u = 0; u < 8; u++) {
#pragma unroll
            for (int s = 0; s < SLOTS; s++) {
                float a = ber[s];
#pragma unroll
                for (int v = 0; v < 6; v++) a = fmaf(ear[u][v], wr[s][v], a);
                float xv = (CIN == 1) ? hprev[sv[u]] : hprev[sv[u] * CIN + iof[s]];
                acc[s] = fmaf(xv, fmaxf(a, 0.f), acc[s]);
            }
        }
    }
    for (; p < p1; ++p) {
        int2 pr = pairs[p];
        const float2* e2 = (const float2*)(ea + (size_t)pr.y * 6);
        float2 a2 = e2[0], b2 = e2[1], c2 = e2[2];
        float ear[6] = {a2.x, a2.y, b2.x, b2.y, c2.x, c2.y};
#pragma unroll
        for (int s = 0; s < SLOTS; s++) {
            float a = ber[s];
#pragma unroll
            for (int v = 0; v < 6; v++) a = fmaf(ear[v], wr[s][v], a);
            float xv = (CIN == 1) ? hprev[pr.x] : hprev[pr.x * CIN + iof[s]];
            acc[s] = fmaf(xv, fmaxf(a, 0.f), acc[s]);
        }
    }

    if constexpr (CIN == 1) {
        // j == o directly; no cross-i reduction needed
        if (tid < J) atomicAdd(&agg[n * COUT + tid], acc[0]);
    } else {
        __syncthreads();
#pragma unroll
        for (int s = 0; s < SLOTS; s++) {
            int j = tid + s * BLK;
            if (j < J) lds_acc[j] = acc[s];
        }
        __syncthreads();
        if (tid < COUT) {
            float sum = 0.f;
#pragma unroll
            for (int i = 0; i < CIN; i++) sum += lds_acc[i * COUT + tid];
            atomicAdd(&agg[n * COUT + tid], sum);
        }
    }
}

// ---------------------------------------------------------------------------
// Finalize: mean + root-weight + bias + relu
// ---------------------------------------------------------------------------
template <int CIN, int COUT>
__global__ __launch_bounds__(64) void nnconv_fin(const float* __restrict__ agg,
                                                 const int* __restrict__ offs,
                                                 const float* __restrict__ hprev,
                                                 const float* __restrict__ root,
                                                 const float* __restrict__ bias,
                                                 float* __restrict__ hout) {
    int n = blockIdx.x;
    int t = threadIdx.x;
    if (t >= COUT) return;
    int cnt = offs[n + 1] - offs[n];
    float inv = 1.f / fmaxf((float)cnt, 1.f);
    float v = agg[n * COUT + t] * inv;
#pragma unroll
    for (int i = 0; i < CIN; i++) v = fmaf(hprev[n * CIN + i], root[i * COUT + t], v);
    v += bias[t];
    hout[n * COUT + t] = fmaxf(v, 0.f);
}

// ---------------------------------------------------------------------------
// CBT: out[i,j] = sum_k |h3[i,k] - h3[j,k]|, h3 is [512,5]
// ---------------------------------------------------------------------------
__global__ __launch_bounds__(256) void cbt_kernel(const float* __restrict__ h3,
                                                  float* __restrict__ out) {
    __shared__ float lh[N_NODES * 5];
    int tid = threadIdx.x;
    for (int idx = tid; idx < N_NODES * 5; idx += 256) lh[idx] = h3[idx];
    __syncthreads();
    int i = blockIdx.x;
    float hi[5];
#pragma unroll
    for (int k = 0; k < 5; k++) hi[k] = lh[i * 5 + k];
    for (int j = tid; j < N_NODES; j += 256) {
        float sacc = 0.f;
#pragma unroll
        for (int k = 0; k < 5; k++) sacc += fabsf(hi[k] - lh[j * 5 + k]);
        out[i * N_NODES + j] = sacc;
    }
}

// ---------------------------------------------------------------------------
extern "C" void kernel_launch(void* const* d_in, const int* in_sizes, int n_in,
                              void* d_out, int out_size, void* d_ws, size_t ws_size,
                              hipStream_t stream) {
    const float* x = (const float*)d_in[0];
    const float* edge_attr = (const float*)d_in[1];
    const int* edge_index = (const int*)d_in[2];
    const float* We1 = (const float*)d_in[3];
    const float* be1 = (const float*)d_in[4];
    const float* root1 = (const float*)d_in[5];
    const float* b1 = (const float*)d_in[6];
    const float* We2 = (const float*)d_in[7];
    const float* be2 = (const float*)d_in[8];
    const float* root2 = (const float*)d_in[9];
    const float* b2 = (const float*)d_in[10];
    const float* We3 = (const float*)d_in[11];
    const float* be3 = (const float*)d_in[12];
    const float* root3 = (const float*)d_in[13];
    const float* b3 = (const float*)d_in[14];

    const int E = N_EDGES;
    const int* src = edge_index;
    const int* dst = edge_index + E;

    char* ws = (char*)d_ws;
    int* offs = (int*)(ws + 0);              // 513 ints (2052 B)
    int* cnt = (int*)(ws + 4096);            // 512 ints
    int* cursor = (int*)(ws + 6144);         // 512 ints
    int2* pairs = (int2*)(ws + 8192);        // E int2 -> ends 2,105,344
    float* agg1 = (float*)(ws + 2105344);    // 512*36 -> 2,179,072
    float* agg2 = (float*)(ws + 2179072);    // 512*24 -> 2,228,224
    float* agg3 = (float*)(ws + 2228224);    // 512*5  -> 2,238,464
    float* h1 = (float*)(ws + 2238464);      // 512*36 -> 2,312,192
    float* h2 = (float*)(ws + 2312192);      // 512*24 -> 2,361,344
    float* h3 = (float*)(ws + 2361344);      // 512*5  -> 2,371,584

    hipMemsetAsync(cnt, 0, N_NODES * sizeof(int), stream);
    hipMemsetAsync(agg1, 0, 2238464 - 2105344, stream);  // agg1+agg2+agg3

    count_kernel<<<128, 256, 0, stream>>>(dst, cnt, E);
    scan_kernel<<<1, 512, 0, stream>>>(cnt, offs, cursor);
    scatter_kernel<<<E / 256, 256, 0, stream>>>(src, dst, cursor, pairs, E);

    nnconv_edges<1, 36, 64, 16><<<N_NODES * 16, 64, 0, stream>>>(x, edge_attr, pairs, offs, We1, be1, agg1);
    nnconv_fin<1, 36><<<N_NODES, 64, 0, stream>>>(agg1, offs, x, root1, b1, h1);

    nnconv_edges<36, 24, 256, 8><<<N_NODES * 8, 256, 0, stream>>>(h1, edge_attr, pairs, offs, We2, be2, agg2);
    nnconv_fin<36, 24><<<N_NODES, 64, 0, stream>>>(agg2, offs, h1, root2, b2, h2);

    nnconv_edges<24, 5, 128, 8><<<N_NODES * 8, 128, 0, stream>>>(h2, edge_attr, pairs, offs, We3, be3, agg3);
    nnconv_fin<24, 5><<<N_NODES, 64, 0, stream>>>(agg3, offs, h2, root3, b3, h3);

    cbt_kernel<<<N_NODES, 256, 0, stream>>>(h3, (float*)d_out);
}

// Round 3
// 266.629 us; speedup vs baseline: 1.7962x; 1.1538x over previous
//
#include <hip/hip_runtime.h>
#include <hip/hip_bf16.h>

#define N_NODES 512
#define N_EDGES (512 * 512)

typedef __attribute__((ext_vector_type(2))) _Float16 half2v;

#if defined(__has_builtin)
#if __has_builtin(__builtin_amdgcn_fdot2)
#define FDOT2(a, b, c) __builtin_amdgcn_fdot2((a), (b), (c), false)
#endif
#endif
#ifndef FDOT2
static __device__ inline float fdot2_sw(half2v a, half2v b, float c) {
    return (float)a.x * (float)b.x + (float)a.y * (float)b.y + c;
}
#define FDOT2(a, b, c) fdot2_sw((a), (b), (c))
#endif

static __device__ inline unsigned pack_h2(float x, float y) {
    union { _Float16 h[2]; unsigned u; } c;
    c.h[0] = (_Float16)x;
    c.h[1] = (_Float16)y;
    return c.u;
}
static __device__ inline half2v bits_h2(int b) {
    union { int i; half2v h; } c;
    c.i = b;
    return c.h;
}

// ---------------------------------------------------------------------------
// Counting sort by dst. Edge record: int4 {ea01_f16x2, ea23_f16x2, ea45_f16x2, src}
// ---------------------------------------------------------------------------
__global__ __launch_bounds__(256) void count_kernel(const int* __restrict__ dst,
                                                    int* __restrict__ cnt, int E) {
    __shared__ int h[N_NODES];
    int tid = threadIdx.x;
    for (int i = tid; i < N_NODES; i += 256) h[i] = 0;
    __syncthreads();
    for (int e = blockIdx.x * 256 + tid; e < E; e += gridDim.x * 256)
        atomicAdd(&h[dst[e]], 1);
    __syncthreads();
    for (int i = tid; i < N_NODES; i += 256) {
        int v = h[i];
        if (v) atomicAdd(&cnt[i], v);
    }
}

__global__ __launch_bounds__(512) void scan_kernel(const int* __restrict__ cnt,
                                                   int* __restrict__ offs,
                                                   int* __restrict__ cursor) {
    __shared__ int buf[N_NODES];
    int t = threadIdx.x;
    int v = cnt[t];
    buf[t] = v;
    __syncthreads();
    for (int d = 1; d < N_NODES; d <<= 1) {
        int add = (t >= d) ? buf[t - d] : 0;
        __syncthreads();
        buf[t] += add;
        __syncthreads();
    }
    offs[t + 1] = buf[t];
    if (t == 0) offs[0] = 0;
    cursor[t] = buf[t] - v;  // exclusive prefix = bucket start
}

__global__ __launch_bounds__(256) void scatter_kernel(const int* __restrict__ src,
                                                      const int* __restrict__ dst,
                                                      const float* __restrict__ ea,
                                                      int* __restrict__ cursor,
                                                      int4* __restrict__ ed4, int E) {
    int e = blockIdx.x * 256 + threadIdx.x;
    if (e < E) {
        const float* a = ea + (size_t)e * 6;
        float a0 = a[0], a1 = a[1], a2 = a[2], a3 = a[3], a4 = a[4], a5 = a[5];
        int p = atomicAdd(&cursor[dst[e]], 1);
        int4 r;
        r.x = (int)pack_h2(a0, a1);
        r.y = (int)pack_h2(a2, a3);
        r.z = (int)pack_h2(a4, a5);
        r.w = src[e];
        ed4[p] = r;
    }
}

// ---------------------------------------------------------------------------
// NNConv edge pipeline. Lane l (< CIN * COUT/OG) owns input-feature i = l/OPL
// and OG consecutive outputs og..og+OG-1. Per edge: ONE int4 record load
// (uniform, broadcast), ONE x[src][i] gather, and per o: 3 x v_dot2_f32_f16
// + max + fp32 accumulate-FMA. Partials combined via atomicAdd on agg[n,o].
// ---------------------------------------------------------------------------
template <int CIN, int COUT, int OG, int BLK, int G>
__global__ __launch_bounds__(BLK) void nnconv_edges(
    const float* __restrict__ hprev,  // [512, CIN]
    const int4* __restrict__ ed4,     // [E] sorted-by-dst edge records
    const int* __restrict__ offs,     // [513]
    const float* __restrict__ We,     // [6, CIN*COUT] fp32
    const float* __restrict__ be,     // [CIN*COUT]
    float* __restrict__ agg)          // [512, COUT] pre-zeroed
{
    constexpr int J = CIN * COUT;
    constexpr int OPL = COUT / OG;  // o-groups per input feature
    constexpr int A = CIN * OPL;    // active lanes

    const int n = blockIdx.x / G;
    const int g = blockIdx.x % G;
    const int tid = threadIdx.x;
    const bool act = (tid < A);
    const int i = act ? tid / OPL : 0;
    const int og = act ? (tid % OPL) * OG : 0;

    half2v wrp[OG][3];
    float ber[OG], acc[OG];
#pragma unroll
    for (int k = 0; k < OG; k++) {
        acc[k] = 0.f;
        int j = i * COUT + og + k;
        if (act) {
            ber[k] = be[j];
#pragma unroll
            for (int t = 0; t < 3; t++)
                wrp[k][t] = bits_h2((int)pack_h2(We[(2 * t) * J + j], We[(2 * t + 1) * J + j]));
        } else {
            ber[k] = 0.f;
#pragma unroll
            for (int t = 0; t < 3; t++) wrp[k][t] = bits_h2(0);
        }
    }

    const int start = offs[n];
    const int end = offs[n + 1];
    const int len = end - start;
    const int per = (len + G - 1) / G;
    int p = start + g * per;
    int p1 = p + per;
    if (p1 > end) p1 = end;

    const float* hp_i = hprev + i;  // lane's feature column

    for (; p + 8 <= p1; p += 8) {
        const int4* eb = ed4 + p;
        int4 ed[8];
#pragma unroll
        for (int u = 0; u < 8; u++) ed[u] = eb[u];
        float xv[8];
#pragma unroll
        for (int u = 0; u < 8; u++) xv[u] = hp_i[ed[u].w * CIN];
#pragma unroll
        for (int u = 0; u < 8; u++) {
            half2v e01 = bits_h2(ed[u].x), e23 = bits_h2(ed[u].y), e45 = bits_h2(ed[u].z);
#pragma unroll
            for (int k = 0; k < OG; k++) {
                float z = FDOT2(e45, wrp[k][2],
                        FDOT2(e23, wrp[k][1],
                        FDOT2(e01, wrp[k][0], ber[k])));
                acc[k] = fmaf(xv[u], fmaxf(z, 0.f), acc[k]);
            }
        }
    }
    for (; p < p1; ++p) {
        int4 ed = ed4[p];
        float xv = hp_i[ed.w * CIN];
        half2v e01 = bits_h2(ed.x), e23 = bits_h2(ed.y), e45 = bits_h2(ed.z);
#pragma unroll
        for (int k = 0; k < OG; k++) {
            float z = FDOT2(e45, wrp[k][2],
                    FDOT2(e23, wrp[k][1],
                    FDOT2(e01, wrp[k][0], ber[k])));
            acc[k] = fmaf(xv, fmaxf(z, 0.f), acc[k]);
        }
    }

    if constexpr (CIN == 1) {
        if (act) atomicAdd(&agg[n * COUT + og], acc[0]);
    } else {
        __shared__ float lds_acc[J];
        if (act) {
#pragma unroll
            for (int k = 0; k < OG; k++) lds_acc[i * COUT + og + k] = acc[k];
        }
        __syncthreads();
        if (tid < COUT) {
            float sum = 0.f;
#pragma unroll
            for (int ii = 0; ii < CIN; ii++) sum += lds_acc[ii * COUT + tid];
            atomicAdd(&agg[n * COUT + tid], sum);
        }
    }
}

// ---------------------------------------------------------------------------
// Finalize: mean + root-weight + bias + relu
// ---------------------------------------------------------------------------
template <int CIN, int COUT>
__global__ __launch_bounds__(64) void nnconv_fin(const float* __restrict__ agg,
                                                 const int* __restrict__ offs,
                                                 const float* __restrict__ hprev,
                                                 const float* __restrict__ root,
                                                 const float* __restrict__ bias,
                                                 float* __restrict__ hout) {
    int n = blockIdx.x;
    int t = threadIdx.x;
    if (t >= COUT) return;
    int cnt = offs[n + 1] - offs[n];
    float inv = 1.f / fmaxf((float)cnt, 1.f);
    float v = agg[n * COUT + t] * inv;
#pragma unroll
    for (int i = 0; i < CIN; i++) v = fmaf(hprev[n * CIN + i], root[i * COUT + t], v);
    v += bias[t];
    hout[n * COUT + t] = fmaxf(v, 0.f);
}

// ---------------------------------------------------------------------------
// CBT: out[i,j] = sum_k |h3[i,k] - h3[j,k]|, h3 is [512,5]
// ---------------------------------------------------------------------------
__global__ __launch_bounds__(256) void cbt_kernel(const float* __restrict__ h3,
                                                  float* __restrict__ out) {
    __shared__ float lh[N_NODES * 5];
    int tid = threadIdx.x;
    for (int idx = tid; idx < N_NODES * 5; idx += 256) lh[idx] = h3[idx];
    __syncthreads();
    int i = blockIdx.x;
    float hi[5];
#pragma unroll
    for (int k = 0; k < 5; k++) hi[k] = lh[i * 5 + k];
    for (int j = tid; j < N_NODES; j += 256) {
        float sacc = 0.f;
#pragma unroll
        for (int k = 0; k < 5; k++) sacc += fabsf(hi[k] - lh[j * 5 + k]);
        out[i * N_NODES + j] = sacc;
    }
}

// ---------------------------------------------------------------------------
extern "C" void kernel_launch(void* const* d_in, const int* in_sizes, int n_in,
                              void* d_out, int out_size, void* d_ws, size_t ws_size,
                              hipStream_t stream) {
    const float* x = (const float*)d_in[0];
    const float* edge_attr = (const float*)d_in[1];
    const int* edge_index = (const int*)d_in[2];
    const float* We1 = (const float*)d_in[3];
    const float* be1 = (const float*)d_in[4];
    const float* root1 = (const float*)d_in[5];
    const float* b1 = (const float*)d_in[6];
    const float* We2 = (const float*)d_in[7];
    const float* be2 = (const float*)d_in[8];
    const float* root2 = (const float*)d_in[9];
    const float* b2 = (const float*)d_in[10];
    const float* We3 = (const float*)d_in[11];
    const float* be3 = (const float*)d_in[12];
    const float* root3 = (const float*)d_in[13];
    const float* b3 = (const float*)d_in[14];

    const int E = N_EDGES;
    const int* src = edge_index;
    const int* dst = edge_index + E;

    char* ws = (char*)d_ws;
    int* offs = (int*)(ws + 0);               // 513 ints
    int* cnt = (int*)(ws + 4096);             // 512 ints
    int* cursor = (int*)(ws + 6144);          // 512 ints
    int4* ed4 = (int4*)(ws + 8192);           // E*16B -> ends 4,202,496
    float* agg1 = (float*)(ws + 4202496);     // 512*36 -> 4,276,224
    float* agg2 = (float*)(ws + 4276224);     // 512*24 -> 4,325,376
    float* agg3 = (float*)(ws + 4325376);     // 512*5  -> 4,335,616
    float* h1 = (float*)(ws + 4335616);       // 512*36 -> 4,409,344
    float* h2 = (float*)(ws + 4409344);       // 512*24 -> 4,458,496
    float* h3 = (float*)(ws + 4458496);       // 512*5  -> 4,468,736

    hipMemsetAsync(cnt, 0, N_NODES * sizeof(int), stream);
    hipMemsetAsync(agg1, 0, 4335616 - 4202496, stream);  // agg1+agg2+agg3

    count_kernel<<<128, 256, 0, stream>>>(dst, cnt, E);
    scan_kernel<<<1, 512, 0, stream>>>(cnt, offs, cursor);
    scatter_kernel<<<E / 256, 256, 0, stream>>>(src, dst, edge_attr, cursor, ed4, E);

    // L1: CIN=1, COUT=36, OG=1 -> 36 active lanes, BLK=64, G=16
    nnconv_edges<1, 36, 1, 64, 16><<<N_NODES * 16, 64, 0, stream>>>(x, ed4, offs, We1, be1, agg1);
    nnconv_fin<1, 36><<<N_NODES, 64, 0, stream>>>(agg1, offs, x, root1, b1, h1);

    // L2: CIN=36, COUT=24, OG=4 -> 216 active lanes, BLK=256, G=8
    nnconv_edges<36, 24, 4, 256, 8><<<N_NODES * 8, 256, 0, stream>>>(h1, ed4, offs, We2, be2, agg2);
    nnconv_fin<36, 24><<<N_NODES, 64, 0, stream>>>(agg2, offs, h1, root2, b2, h2);

    // L3: CIN=24, COUT=5, OG=1 -> 120 active lanes, BLK=128, G=8
    nnconv_edges<24, 5, 1, 128, 8><<<N_NODES * 8, 128, 0, stream>>>(h2, ed4, offs, We3, be3, agg3);
    nnconv_fin<24, 5><<<N_NODES, 64, 0, stream>>>(agg3, offs, h2, root3, b3, h3);

    cbt_kernel<<<N_NODES, 256, 0, stream>>>(h3, (float*)d_out);
}

// Round 4
// 202.522 us; speedup vs baseline: 2.3648x; 1.3165x over previous
//
#include <hip/hip_runtime.h>
#include <hip/hip_bf16.h>

#define N_NODES 512
#define N_EDGES (512 * 512)
#define NBLK 256                 // sort blocks
#define EPB (N_EDGES / NBLK)     // 1024 edges per sort block

typedef __attribute__((ext_vector_type(2))) _Float16 half2v;

#if defined(__has_builtin)
#if __has_builtin(__builtin_amdgcn_fdot2)
#define FDOT2(a, b, c) __builtin_amdgcn_fdot2((a), (b), (c), false)
#endif
#endif
#ifndef FDOT2
static __device__ inline float fdot2_sw(half2v a, half2v b, float c) {
    return (float)a.x * (float)b.x + (float)a.y * (float)b.y + c;
}
#define FDOT2(a, b, c) fdot2_sw((a), (b), (c))
#endif

static __device__ inline unsigned pack_h2(float x, float y) {
    union { _Float16 h[2]; unsigned u; } c;
    c.h[0] = (_Float16)x;
    c.h[1] = (_Float16)y;
    return c.u;
}
static __device__ inline half2v bits_h2(int b) {
    union { int i; half2v h; } c;
    c.i = b;
    return c.h;
}

// ---------------------------------------------------------------------------
// Deterministic counting sort by dst — NO device-scope atomics.
// count: per-block LDS histogram -> bcnt[block][512]
// ---------------------------------------------------------------------------
__global__ __launch_bounds__(256) void count_kernel(const int* __restrict__ dst,
                                                    int* __restrict__ bcnt) {
    __shared__ int h[N_NODES];
    int tid = threadIdx.x;
    int b = blockIdx.x;
    h[tid] = 0;
    h[tid + 256] = 0;
    __syncthreads();
#pragma unroll
    for (int k = 0; k < EPB / 256; k++)
        atomicAdd(&h[dst[b * EPB + k * 256 + tid]], 1);
    __syncthreads();
    bcnt[b * N_NODES + tid] = h[tid];
    bcnt[b * N_NODES + tid + 256] = h[tid + 256];
}

// scan: offs[513] global segment starts; base[block][bucket] per-block starts.
__global__ __launch_bounds__(512) void scan_kernel(const int* __restrict__ bcnt,
                                                   int* __restrict__ offs,
                                                   int* __restrict__ base) {
    __shared__ int buf[N_NODES];
    int t = threadIdx.x;
    int sum = 0;
    for (int b = 0; b < NBLK; b++) sum += bcnt[b * N_NODES + t];  // coalesced rows
    buf[t] = sum;
    __syncthreads();
    for (int d = 1; d < N_NODES; d <<= 1) {
        int add = (t >= d) ? buf[t - d] : 0;
        __syncthreads();
        buf[t] += add;
        __syncthreads();
    }
    offs[t + 1] = buf[t];
    if (t == 0) offs[0] = 0;
    int run = buf[t] - sum;  // exclusive global start of bucket t
    for (int b = 0; b < NBLK; b++) {
        base[b * N_NODES + t] = run;
        run += bcnt[b * N_NODES + t];
    }
}

// scatter: LDS cursor seeded from base; LDS atomics only; packed f16 record.
__global__ __launch_bounds__(256) void scatter_kernel(const int* __restrict__ src,
                                                      const int* __restrict__ dst,
                                                      const float* __restrict__ ea,
                                                      const int* __restrict__ base,
                                                      int4* __restrict__ ed4) {
    __shared__ int lcur[N_NODES];
    int tid = threadIdx.x;
    int b = blockIdx.x;
    lcur[tid] = base[b * N_NODES + tid];
    lcur[tid + 256] = base[b * N_NODES + tid + 256];
    __syncthreads();
#pragma unroll
    for (int k = 0; k < EPB / 256; k++) {
        int e = b * EPB + k * 256 + tid;
        const float* a = ea + (size_t)e * 6;
        float a0 = a[0], a1 = a[1], a2 = a[2], a3 = a[3], a4 = a[4], a5 = a[5];
        int p = atomicAdd(&lcur[dst[e]], 1);  // LDS atomic, returns slot
        int4 r;
        r.x = (int)pack_h2(a0, a1);
        r.y = (int)pack_h2(a2, a3);
        r.z = (int)pack_h2(a4, a5);
        r.w = src[e];
        ed4[p] = r;
    }
}

// ---------------------------------------------------------------------------
// NNConv edge pipeline. Lane l (< CIN * COUT/OG) owns input-feature i = l/OPL
// and OG consecutive outputs og..og+OG-1. Per edge: ONE int4 record load
// (uniform, broadcast), ONE x[src][i] gather, and per o: 3 x v_dot2_f32_f16
// + max + fp32 accumulate-FMA. Partials combined via atomicAdd on agg[n,o].
// ---------------------------------------------------------------------------
template <int CIN, int COUT, int OG, int BLK, int G>
__global__ __launch_bounds__(BLK) void nnconv_edges(
    const float* __restrict__ hprev,  // [512, CIN]
    const int4* __restrict__ ed4,     // [E] sorted-by-dst edge records
    const int* __restrict__ offs,     // [513]
    const float* __restrict__ We,     // [6, CIN*COUT] fp32
    const float* __restrict__ be,     // [CIN*COUT]
    float* __restrict__ agg)          // [512, COUT] pre-zeroed
{
    constexpr int J = CIN * COUT;
    constexpr int OPL = COUT / OG;  // o-groups per input feature
    constexpr int A = CIN * OPL;    // active lanes

    const int n = blockIdx.x / G;
    const int g = blockIdx.x % G;
    const int tid = threadIdx.x;
    const bool act = (tid < A);
    const int i = act ? tid / OPL : 0;
    const int og = act ? (tid % OPL) * OG : 0;

    half2v wrp[OG][3];
    float ber[OG], acc[OG];
#pragma unroll
    for (int k = 0; k < OG; k++) {
        acc[k] = 0.f;
        int j = i * COUT + og + k;
        if (act) {
            ber[k] = be[j];
#pragma unroll
            for (int t = 0; t < 3; t++)
                wrp[k][t] = bits_h2((int)pack_h2(We[(2 * t) * J + j], We[(2 * t + 1) * J + j]));
        } else {
            ber[k] = 0.f;
#pragma unroll
            for (int t = 0; t < 3; t++) wrp[k][t] = bits_h2(0);
        }
    }

    const int start = offs[n];
    const int end = offs[n + 1];
    const int len = end - start;
    const int per = (len + G - 1) / G;
    int p = start + g * per;
    int p1 = p + per;
    if (p1 > end) p1 = end;

    const float* hp_i = hprev + i;  // lane's feature column

    for (; p + 8 <= p1; p += 8) {
        const int4* eb = ed4 + p;
        int4 ed[8];
#pragma unroll
        for (int u = 0; u < 8; u++) ed[u] = eb[u];
        float xv[8];
#pragma unroll
        for (int u = 0; u < 8; u++) xv[u] = hp_i[ed[u].w * CIN];
#pragma unroll
        for (int u = 0; u < 8; u++) {
            half2v e01 = bits_h2(ed[u].x), e23 = bits_h2(ed[u].y), e45 = bits_h2(ed[u].z);
#pragma unroll
            for (int k = 0; k < OG; k++) {
                float z = FDOT2(e45, wrp[k][2],
                        FDOT2(e23, wrp[k][1],
                        FDOT2(e01, wrp[k][0], ber[k])));
                acc[k] = fmaf(xv[u], fmaxf(z, 0.f), acc[k]);
            }
        }
    }
    for (; p < p1; ++p) {
        int4 ed = ed4[p];
        float xv = hp_i[ed.w * CIN];
        half2v e01 = bits_h2(ed.x), e23 = bits_h2(ed.y), e45 = bits_h2(ed.z);
#pragma unroll
        for (int k = 0; k < OG; k++) {
            float z = FDOT2(e45, wrp[k][2],
                    FDOT2(e23, wrp[k][1],
                    FDOT2(e01, wrp[k][0], ber[k])));
            acc[k] = fmaf(xv, fmaxf(z, 0.f), acc[k]);
        }
    }

    if constexpr (CIN == 1) {
        if (act) atomicAdd(&agg[n * COUT + og], acc[0]);
    } else {
        __shared__ float lds_acc[J];
        if (act) {
#pragma unroll
            for (int k = 0; k < OG; k++) lds_acc[i * COUT + og + k] = acc[k];
        }
        __syncthreads();
        if (tid < COUT) {
            float sum = 0.f;
#pragma unroll
            for (int ii = 0; ii < CIN; ii++) sum += lds_acc[ii * COUT + tid];
            atomicAdd(&agg[n * COUT + tid], sum);
        }
    }
}

// ---------------------------------------------------------------------------
// Finalize: mean + root-weight + bias + relu
// ---------------------------------------------------------------------------
template <int CIN, int COUT>
__global__ __launch_bounds__(64) void nnconv_fin(const float* __restrict__ agg,
                                                 const int* __restrict__ offs,
                                                 const float* __restrict__ hprev,
                                                 const float* __restrict__ root,
                                                 const float* __restrict__ bias,
                                                 float* __restrict__ hout) {
    int n = blockIdx.x;
    int t = threadIdx.x;
    if (t >= COUT) return;
    int cnt = offs[n + 1] - offs[n];
    float inv = 1.f / fmaxf((float)cnt, 1.f);
    float v = agg[n * COUT + t] * inv;
#pragma unroll
    for (int i = 0; i < CIN; i++) v = fmaf(hprev[n * CIN + i], root[i * COUT + t], v);
    v += bias[t];
    hout[n * COUT + t] = fmaxf(v, 0.f);
}

// ---------------------------------------------------------------------------
// CBT: out[i,j] = sum_k |h3[i,k] - h3[j,k]|, h3 is [512,5]
// ---------------------------------------------------------------------------
__global__ __launch_bounds__(256) void cbt_kernel(const float* __restrict__ h3,
                                                  float* __restrict__ out) {
    __shared__ float lh[N_NODES * 5];
    int tid = threadIdx.x;
    for (int idx = tid; idx < N_NODES * 5; idx += 256) lh[idx] = h3[idx];
    __syncthreads();
    int i = blockIdx.x;
    float hi[5];
#pragma unroll
    for (int k = 0; k < 5; k++) hi[k] = lh[i * 5 + k];
    for (int j = tid; j < N_NODES; j += 256) {
        float sacc = 0.f;
#pragma unroll
        for (int k = 0; k < 5; k++) sacc += fabsf(hi[k] - lh[j * 5 + k]);
        out[i * N_NODES + j] = sacc;
    }
}

// ---------------------------------------------------------------------------
extern "C" void kernel_launch(void* const* d_in, const int* in_sizes, int n_in,
                              void* d_out, int out_size, void* d_ws, size_t ws_size,
                              hipStream_t stream) {
    const float* x = (const float*)d_in[0];
    const float* edge_attr = (const float*)d_in[1];
    const int* edge_index = (const int*)d_in[2];
    const float* We1 = (const float*)d_in[3];
    const float* be1 = (const float*)d_in[4];
    const float* root1 = (const float*)d_in[5];
    const float* b1 = (const float*)d_in[6];
    const float* We2 = (const float*)d_in[7];
    const float* be2 = (const float*)d_in[8];
    const float* root2 = (const float*)d_in[9];
    const float* b2 = (const float*)d_in[10];
    const float* We3 = (const float*)d_in[11];
    const float* be3 = (const float*)d_in[12];
    const float* root3 = (const float*)d_in[13];
    const float* b3 = (const float*)d_in[14];

    const int E = N_EDGES;
    const int* src = edge_index;
    const int* dst = edge_index + E;

    char* ws = (char*)d_ws;
    int* offs = (int*)(ws + 0);               // 513 ints -> pad to 4096
    int* bcnt = (int*)(ws + 4096);            // 256*512 ints -> ends 528384
    int* base = (int*)(ws + 528384);          // 256*512 ints -> ends 1052672
    int4* ed4 = (int4*)(ws + 1052672);        // E*16B -> ends 5246976
    float* agg1 = (float*)(ws + 5246976);     // 512*36 -> 5320704
    float* agg2 = (float*)(ws + 5320704);     // 512*24 -> 5369856
    float* agg3 = (float*)(ws + 5369856);     // 512*5  -> 5380096
    float* h1 = (float*)(ws + 5380096);       // 512*36 -> 5453824
    float* h2 = (float*)(ws + 5453824);       // 512*24 -> 5502976
    float* h3 = (float*)(ws + 5502976);       // 512*5  -> 5513216

    hipMemsetAsync(agg1, 0, 5380096 - 5246976, stream);  // agg1+agg2+agg3

    count_kernel<<<NBLK, 256, 0, stream>>>(dst, bcnt);
    scan_kernel<<<1, 512, 0, stream>>>(bcnt, offs, base);
    scatter_kernel<<<NBLK, 256, 0, stream>>>(src, dst, edge_attr, base, ed4);

    // L1: CIN=1, COUT=36, OG=1 -> 36 active lanes, BLK=64, G=16
    nnconv_edges<1, 36, 1, 64, 16><<<N_NODES * 16, 64, 0, stream>>>(x, ed4, offs, We1, be1, agg1);
    nnconv_fin<1, 36><<<N_NODES, 64, 0, stream>>>(agg1, offs, x, root1, b1, h1);

    // L2: CIN=36, COUT=24, OG=4 -> 216 active lanes, BLK=256, G=8
    nnconv_edges<36, 24, 4, 256, 8><<<N_NODES * 8, 256, 0, stream>>>(h1, ed4, offs, We2, be2, agg2);
    nnconv_fin<36, 24><<<N_NODES, 64, 0, stream>>>(agg2, offs, h1, root2, b2, h2);

    // L3: CIN=24, COUT=5, OG=1 -> 120 active lanes, BLK=128, G=8
    nnconv_edges<24, 5, 1, 128, 8><<<N_NODES * 8, 128, 0, stream>>>(h2, ed4, offs, We3, be3, agg3);
    nnconv_fin<24, 5><<<N_NODES, 64, 0, stream>>>(agg3, offs, h2, root3, b3, h3);

    cbt_kernel<<<N_NODES, 256, 0, stream>>>(h3, (float*)d_out);
}